// Round 1
// baseline (361.979 us; speedup 1.0000x reference)
//
#include <hip/hip_runtime.h>
#include <hip/hip_bf16.h>
#include <stdint.h>

typedef __attribute__((ext_vector_type(8))) __bf16 bf16x8;
typedef __attribute__((ext_vector_type(4))) float f32x4;

#define GLOAD(g, l) __builtin_amdgcn_global_load_lds(                      \
    (const __attribute__((address_space(1))) void*)(g),                    \
    (__attribute__((address_space(3))) void*)(l), 16, 0, 0)

__device__ __forceinline__ unsigned short f2bf(float f) {
  // round-to-nearest-even f32 -> bf16 (no NaN in this workload)
  unsigned u = __float_as_uint(f);
  u = (u + 0x7FFFu + ((u >> 16) & 1u)) >> 16;
  return (unsigned short)u;
}

// ---- W -> sign(W) as bf16 bits, plus per-block partial sums of |W| ------
__global__ __launch_bounds__(256) void wsign_kernel(
    const float* __restrict__ W, unsigned short* __restrict__ S,
    float* __restrict__ partials) {
  const int tid = threadIdx.x;
  const int stride = gridDim.x * 256;
  const int total4 = (4096 * 4096) / 4;
  float s = 0.f;
  for (int i = blockIdx.x * 256 + tid; i < total4; i += stride) {
    float4 w = reinterpret_cast<const float4*>(W)[i];
    ushort4 o;
    o.x = w.x > 0.f ? 0x3F80 : (w.x < 0.f ? 0xBF80 : 0);
    o.y = w.y > 0.f ? 0x3F80 : (w.y < 0.f ? 0xBF80 : 0);
    o.z = w.z > 0.f ? 0x3F80 : (w.z < 0.f ? 0xBF80 : 0);
    o.w = w.w > 0.f ? 0x3F80 : (w.w < 0.f ? 0xBF80 : 0);
    reinterpret_cast<ushort4*>(S)[i] = o;
    s += fabsf(w.x) + fabsf(w.y) + fabsf(w.z) + fabsf(w.w);
  }
#pragma unroll
  for (int off = 32; off > 0; off >>= 1) s += __shfl_down(s, off, 64);
  __shared__ float sm[4];
  if ((tid & 63) == 0) sm[tid >> 6] = s;
  __syncthreads();
  if (tid == 0) partials[blockIdx.x] = sm[0] + sm[1] + sm[2] + sm[3];
}

// ---- x f32 -> bf16 ------------------------------------------------------
__global__ __launch_bounds__(256) void xconv_kernel(
    const float* __restrict__ X, unsigned short* __restrict__ XB) {
  const int total4 = (8192 * 4096) / 4;
  const int stride = gridDim.x * 256;
  for (int i = blockIdx.x * 256 + threadIdx.x; i < total4; i += stride) {
    float4 v = reinterpret_cast<const float4*>(X)[i];
    ushort4 o;
    o.x = f2bf(v.x);
    o.y = f2bf(v.y);
    o.z = f2bf(v.z);
    o.w = f2bf(v.w);
    reinterpret_cast<ushort4*>(XB)[i] = o;
  }
}

// ---- deterministic reduce of partials -> scale = mean(|W|) --------------
__global__ __launch_bounds__(256) void finalize_kernel(
    const float* __restrict__ partials, float* __restrict__ scale) {
  const int tid = threadIdx.x;
  float s = 0.f;
  for (int i = tid; i < 2048; i += 256) s += partials[i];
#pragma unroll
  for (int off = 32; off > 0; off >>= 1) s += __shfl_down(s, off, 64);
  __shared__ float sm[4];
  if ((tid & 63) == 0) sm[tid >> 6] = s;
  __syncthreads();
  if (tid == 0) scale[0] = (sm[0] + sm[1] + sm[2] + sm[3]) * (1.0f / 16777216.0f);
}

// ---- bf16 GEMM: C[M][N] = scale * A[M][K] * B[N][K]^T  (m97 structure) --
__global__ __launch_bounds__(256) void gemm_sign_kernel(
    const unsigned short* __restrict__ A,  // bf16 bits, [8192][4096]
    const unsigned short* __restrict__ B,  // bf16 sign, [4096][4096]
    const float* __restrict__ scale_p, float* __restrict__ C) {
  constexpr int M = 8192, N = 4096, K = 4096;
  constexpr int BM = 128, BN = 128, BK = 32;
  __shared__ __align__(16) unsigned short As[BM * BK];
  __shared__ __align__(16) unsigned short Bs[BN * BK];

  const int tid = threadIdx.x;
  const int wave = tid >> 6;
  const int lane = tid & 63;

  // XCD-aware swizzle; nwg = 2048, divisible by 8 -> bijective
  const int nwg = (M / BM) * (N / BN);
  const int bid = blockIdx.x;
  const int swz = (bid & 7) * (nwg / 8) + (bid >> 3);
  const int ntn = N / BN;  // 32
  const int tm = swz / ntn, tn = swz % ntn;
  const long rowBase = (long)tm * BM;
  const long colBase = (long)tn * BN;

  // staging: each thread issues 2 A-loads + 2 B-loads of 16B each per K-step
  const int r4 = lane >> 2;        // 0..15 row within a 16-row stripe
  const int kc = (lane & 3) * 8;   // k-element offset (0,8,16,24)
  const unsigned short* agp0 = A + (rowBase + wave * 16 + r4) * (long)K + kc;
  const unsigned short* agp1 = agp0 + (size_t)64 * K;
  const unsigned short* bgp0 = B + (colBase + wave * 16 + r4) * (long)K + kc;
  const unsigned short* bgp1 = bgp0 + (size_t)64 * K;
  unsigned short* al0 = As + wave * 512 + lane * 8;  // lane0 holds wave base
  unsigned short* al1 = al0 + 2048;
  unsigned short* bl0 = Bs + wave * 512 + lane * 8;
  unsigned short* bl1 = bl0 + 2048;

  // fragment read addresses (ds_read_b128)
  const int wr = wave >> 1, wc = wave & 1;
  const int fr = lane & 15;  // row within 16
  const int fq = lane >> 4;  // k-octet 0..3
  const unsigned short* ar = As + (wr * 64 + fr) * BK + fq * 8;
  const unsigned short* br = Bs + (wc * 64 + fr) * BK + fq * 8;

  f32x4 acc[4][4];
#pragma unroll
  for (int m = 0; m < 4; ++m)
#pragma unroll
    for (int n = 0; n < 4; ++n) acc[m][n] = (f32x4){0.f, 0.f, 0.f, 0.f};

  for (int k0 = 0; k0 < K; k0 += BK) {
    GLOAD(agp0 + k0, al0);
    GLOAD(agp1 + k0, al1);
    GLOAD(bgp0 + k0, bl0);
    GLOAD(bgp1 + k0, bl1);
    __syncthreads();  // drains vmcnt: LDS tile complete

    bf16x8 af[4], bv[4];
#pragma unroll
    for (int m = 0; m < 4; ++m)
      af[m] = *reinterpret_cast<const bf16x8*>(ar + m * 16 * BK);
#pragma unroll
    for (int n = 0; n < 4; ++n)
      bv[n] = *reinterpret_cast<const bf16x8*>(br + n * 16 * BK);
#pragma unroll
    for (int m = 0; m < 4; ++m)
#pragma unroll
      for (int n = 0; n < 4; ++n)
        acc[m][n] = __builtin_amdgcn_mfma_f32_16x16x32_bf16(af[m], bv[n],
                                                            acc[m][n], 0, 0, 0);
    __syncthreads();  // protect LDS before next-iter staging
  }

  const float scale = *scale_p;
#pragma unroll
  for (int m = 0; m < 4; ++m) {
    const long row0 = rowBase + wr * 64 + m * 16 + fq * 4;
#pragma unroll
    for (int n = 0; n < 4; ++n) {
      const long col = colBase + wc * 64 + n * 16 + fr;
      f32x4 v = acc[m][n];
#pragma unroll
      for (int j = 0; j < 4; ++j) C[(row0 + j) * N + col] = v[j] * scale;
    }
  }
}

extern "C" void kernel_launch(void* const* d_in, const int* in_sizes, int n_in,
                              void* d_out, int out_size, void* d_ws,
                              size_t ws_size, hipStream_t stream) {
  const float* x = (const float*)d_in[0];   // [8192][4096] f32
  const float* w = (const float*)d_in[1];   // [4096][4096] f32
  float* out = (float*)d_out;               // [8192][4096] f32

  char* ws = (char*)d_ws;
  unsigned short* xb = (unsigned short*)ws;                   // 64 MiB
  unsigned short* sb = (unsigned short*)(ws + 67108864);      // 32 MiB
  float* partials = (float*)(ws + 100663296);                 // 2048 f32
  float* scale = (float*)(ws + 100663296 + 8192);             // 1 f32

  wsign_kernel<<<2048, 256, 0, stream>>>(w, sb, partials);
  xconv_kernel<<<2048, 256, 0, stream>>>(x, xb);
  finalize_kernel<<<1, 256, 0, stream>>>(partials, scale);
  gemm_sign_kernel<<<2048, 256, 0, stream>>>(xb, sb, scale, out);
}

// Round 2
// 282.986 us; speedup vs baseline: 1.2791x; 1.2791x over previous
//
#include <hip/hip_runtime.h>
#include <hip/hip_bf16.h>
#include <stdint.h>

typedef __attribute__((ext_vector_type(8))) __bf16 bf16x8;
typedef __attribute__((ext_vector_type(4))) float f32x4;

#define GLOAD(g, l) __builtin_amdgcn_global_load_lds(                      \
    (const __attribute__((address_space(1))) void*)(g),                    \
    (__attribute__((address_space(3))) void*)(l), 16, 0, 0)

#define MFMA __builtin_amdgcn_mfma_f32_16x16x32_bf16

__device__ __forceinline__ unsigned short f2bf(float f) {
  unsigned u = __float_as_uint(f);
  u = (u + 0x7FFFu + ((u >> 16) & 1u)) >> 16;
  return (unsigned short)u;
}

// ---- W -> sign(W) as bf16 bits, plus per-block partial sums of |W| ------
__global__ __launch_bounds__(256) void wsign_kernel(
    const float* __restrict__ W, unsigned short* __restrict__ S,
    float* __restrict__ partials) {
  const int tid = threadIdx.x;
  const int stride = gridDim.x * 256;
  const int total4 = (4096 * 4096) / 4;
  float s = 0.f;
  for (int i = blockIdx.x * 256 + tid; i < total4; i += stride) {
    float4 w = reinterpret_cast<const float4*>(W)[i];
    ushort4 o;
    o.x = w.x > 0.f ? 0x3F80 : (w.x < 0.f ? 0xBF80 : 0);
    o.y = w.y > 0.f ? 0x3F80 : (w.y < 0.f ? 0xBF80 : 0);
    o.z = w.z > 0.f ? 0x3F80 : (w.z < 0.f ? 0xBF80 : 0);
    o.w = w.w > 0.f ? 0x3F80 : (w.w < 0.f ? 0xBF80 : 0);
    reinterpret_cast<ushort4*>(S)[i] = o;
    s += fabsf(w.x) + fabsf(w.y) + fabsf(w.z) + fabsf(w.w);
  }
#pragma unroll
  for (int off = 32; off > 0; off >>= 1) s += __shfl_down(s, off, 64);
  __shared__ float sm[4];
  if ((tid & 63) == 0) sm[tid >> 6] = s;
  __syncthreads();
  if (tid == 0) partials[blockIdx.x] = sm[0] + sm[1] + sm[2] + sm[3];
}

// ---- x f32 -> bf16 ------------------------------------------------------
__global__ __launch_bounds__(256) void xconv_kernel(
    const float* __restrict__ X, unsigned short* __restrict__ XB) {
  const int total4 = (8192 * 4096) / 4;
  const int stride = gridDim.x * 256;
  for (int i = blockIdx.x * 256 + threadIdx.x; i < total4; i += stride) {
    float4 v = reinterpret_cast<const float4*>(X)[i];
    ushort4 o;
    o.x = f2bf(v.x);
    o.y = f2bf(v.y);
    o.z = f2bf(v.z);
    o.w = f2bf(v.w);
    reinterpret_cast<ushort4*>(XB)[i] = o;
  }
}

// ---- deterministic reduce of partials -> scale = mean(|W|) --------------
__global__ __launch_bounds__(256) void finalize_kernel(
    const float* __restrict__ partials, float* __restrict__ scale) {
  const int tid = threadIdx.x;
  float s = 0.f;
  for (int i = tid; i < 2048; i += 256) s += partials[i];
#pragma unroll
  for (int off = 32; off > 0; off >>= 1) s += __shfl_down(s, off, 64);
  __shared__ float sm[4];
  if ((tid & 63) == 0) sm[tid >> 6] = s;
  __syncthreads();
  if (tid == 0) scale[0] = (sm[0] + sm[1] + sm[2] + sm[3]) * (1.0f / 16777216.0f);
}

// ---- 256x256x64 8-wave 4-phase bf16 GEMM, C = scale * A * B^T -----------
// LDS slots (16 KiB each): A[par][half] = slot par*2+half; B[par][half] = 4+par*2+half
__global__ __launch_bounds__(512, 2) void gemm_sign_kernel(
    const unsigned short* __restrict__ A,  // [8192][4096] bf16 bits
    const unsigned short* __restrict__ B,  // [4096][4096] bf16 sign
    const float* __restrict__ scale_p, float* __restrict__ C) {
  constexpr int M = 8192, N = 4096, K = 4096;
  constexpr int NT = K / 64;  // 64 K-tiles
  __shared__ __align__(16) unsigned short lds[65536];  // 128 KiB

  const int tid = threadIdx.x;
  const int wid = tid >> 6;
  const int lane = tid & 63;
  const int wr = wid >> 2;        // 0..1 : A half (M-rows)
  const int wc = wid & 3;         // 0..3 : 64-col group (B-rows)
  const int bh = wc >> 1;         // B half slot
  const int bsub = (wc & 1) * 4096;  // element offset within B slot
  const int fr = lane & 15;
  const int fq = lane >> 4;
  const int s0 = (fq ^ (fr & 7)) * 8;  // swizzled k-slot (elements), kk=0; kk=1 is s0^32

  // XCD-aware swizzle; nwg = 32*16 = 512, divisible by 8
  const int bid = blockIdx.x;
  const int swz = (bid & 7) * 64 + (bid >> 3);
  const int tm = swz >> 4, tn = swz & 15;

  // --- staging source addresses (per-thread, pre-inverse-swizzled) ---
  const int srow = tid >> 3;                         // 0..63 (j=1 adds 64; 64%8==0 so g unchanged)
  const int sg = (tid & 7) ^ (srow & 7);             // source col-group
  const unsigned short* aSrc0 = A + (size_t)(tm * 256 + srow) * K + sg * 8;
  const unsigned short* aSrc1 = aSrc0 + (size_t)128 * K;
  const unsigned short* bSrc0 = B + (size_t)(tn * 256 + srow) * K + sg * 8;
  const unsigned short* bSrc1 = bSrc0 + (size_t)128 * K;

#define STAGE(srcBase, slotIdx, koff)                              \
  do {                                                             \
    const unsigned short* _s = (srcBase) + (koff);                 \
    unsigned short* _d = &lds[(slotIdx) * 8192 + wid * 512];       \
    GLOAD(_s, _d);                                                 \
    GLOAD(_s + (size_t)64 * K, _d + 4096);                         \
  } while (0)

  f32x4 acc[8][4];
#pragma unroll
  for (int m = 0; m < 8; ++m)
#pragma unroll
    for (int n = 0; n < 4; ++n) acc[m][n] = (f32x4){0.f, 0.f, 0.f, 0.f};

  // Prologue: A0(0), B0(0), A1(0), B1(0), A0(1)  [issue order defines vmcnt]
  STAGE(aSrc0, 0, 0);
  STAGE(bSrc0, 4, 0);
  STAGE(aSrc1, 1, 0);
  STAGE(bSrc1, 5, 0);
  STAGE(aSrc0, 2, 64);

#define READ_A(dst, aS, mb)                                              \
  do {                                                                   \
    dst[0][0] = *(const bf16x8*)((aS) + (mb)*1024 + s0);                 \
    dst[0][1] = *(const bf16x8*)((aS) + (mb)*1024 + (s0 ^ 32));          \
    dst[1][0] = *(const bf16x8*)((aS) + (mb)*1024 + 1024 + s0);          \
    dst[1][1] = *(const bf16x8*)((aS) + (mb)*1024 + 1024 + (s0 ^ 32));   \
  } while (0)

#define PH_MFMA(av, r0)                                                  \
  do {                                                                   \
    __builtin_amdgcn_s_setprio(1);                                       \
    _Pragma("unroll") for (int i = 0; i < 2; ++i)                        \
        _Pragma("unroll") for (int n = 0; n < 4; ++n) {                  \
      acc[(r0) + i][n] = MFMA(av[i][0], bq[n][0], acc[(r0) + i][n], 0, 0, 0); \
      acc[(r0) + i][n] = MFMA(av[i][1], bq[n][1], acc[(r0) + i][n], 0, 0, 0); \
    }                                                                    \
    __builtin_amdgcn_s_setprio(0);                                       \
  } while (0)

  for (int t = 0; t < NT; ++t) {
    const int par = t & 1;
    const int kn = (t + 1) * 64;
    // --- top-of-tile: counted wait (never 0 except final), then sync ---
    if (t == NT - 1) {
      asm volatile("s_waitcnt vmcnt(0)" ::: "memory");
    } else {
      asm volatile("s_waitcnt vmcnt(2)" ::: "memory");
    }
    __builtin_amdgcn_s_barrier();

    const unsigned short* aS = &lds[(par * 2 + wr) * 8192 + fr * 64];
    const unsigned short* bS = &lds[(4 + par * 2 + bh) * 8192 + bsub + fr * 64];

    // ---- P0: read all B + A m0/m1; stage B0(t+1), A1(t+1) ----
    bf16x8 bq[4][2];
#pragma unroll
    for (int n = 0; n < 4; ++n) {
      bq[n][0] = *(const bf16x8*)(bS + n * 1024 + s0);
      bq[n][1] = *(const bf16x8*)(bS + n * 1024 + (s0 ^ 32));
    }
    bf16x8 a01[2][2];
    READ_A(a01, aS, 0);
    if (t + 1 < NT) {
      STAGE(bSrc0, 4 + (par ^ 1) * 2, kn);
      STAGE(aSrc1, (par ^ 1) * 2 + 1, kn);
    }
    __builtin_amdgcn_s_barrier();
    asm volatile("s_waitcnt lgkmcnt(0)" ::: "memory");
    PH_MFMA(a01, 0);
    __builtin_amdgcn_s_barrier();

    // ---- P1: read A m2/m3; stage B1(t+1) ----
    bf16x8 a23[2][2];
    READ_A(a23, aS, 2);
    if (t + 1 < NT) {
      STAGE(bSrc1, 4 + (par ^ 1) * 2 + 1, kn);
    }
    __builtin_amdgcn_s_barrier();
    asm volatile("s_waitcnt lgkmcnt(0)" ::: "memory");
    PH_MFMA(a23, 2);
    __builtin_amdgcn_s_barrier();

    // ---- P2: read A m4..m7 ----
    bf16x8 a45[2][2], a67[2][2];
    READ_A(a45, aS, 4);
    READ_A(a67, aS, 6);
    __builtin_amdgcn_s_barrier();
    asm volatile("s_waitcnt lgkmcnt(0)" ::: "memory");
    PH_MFMA(a45, 4);
    __builtin_amdgcn_s_barrier();

    // ---- P3: stage A0(t+2) (slot A[par][0]; its readers finished at P2) ----
    if (t + 2 < NT) {
      STAGE(aSrc0, par * 2, (t + 2) * 64);
    }
    PH_MFMA(a67, 6);
    __builtin_amdgcn_s_barrier();
  }

  // ---- epilogue ----
  const float sc = *scale_p;
  const int crow0 = tm * 256 + wr * 128 + fq * 4;
  const int ccol0 = tn * 256 + wc * 64 + fr;
#pragma unroll
  for (int m = 0; m < 8; ++m) {
#pragma unroll
    for (int n = 0; n < 4; ++n) {
      f32x4 v = acc[m][n];
      float* cp = C + (size_t)(crow0 + m * 16) * N + ccol0 + n * 16;
#pragma unroll
      for (int j = 0; j < 4; ++j) cp[(size_t)j * N] = v[j] * sc;
    }
  }
#undef STAGE
#undef READ_A
#undef PH_MFMA
}

extern "C" void kernel_launch(void* const* d_in, const int* in_sizes, int n_in,
                              void* d_out, int out_size, void* d_ws,
                              size_t ws_size, hipStream_t stream) {
  const float* x = (const float*)d_in[0];   // [8192][4096] f32
  const float* w = (const float*)d_in[1];   // [4096][4096] f32
  float* out = (float*)d_out;               // [8192][4096] f32

  char* ws = (char*)d_ws;
  unsigned short* xb = (unsigned short*)ws;                   // 64 MiB
  unsigned short* sb = (unsigned short*)(ws + 67108864);      // 32 MiB
  float* partials = (float*)(ws + 100663296);                 // 2048 f32
  float* scale = (float*)(ws + 100663296 + 8192);             // 1 f32

  wsign_kernel<<<2048, 256, 0, stream>>>(w, sb, partials);
  xconv_kernel<<<2048, 256, 0, stream>>>(x, xb);
  finalize_kernel<<<1, 256, 0, stream>>>(partials, scale);
  gemm_sign_kernel<<<512, 512, 0, stream>>>(xb, sb, scale, out);
}

// Round 3
// 279.158 us; speedup vs baseline: 1.2967x; 1.0137x over previous
//
#include <hip/hip_runtime.h>
#include <hip/hip_bf16.h>
#include <stdint.h>

typedef __attribute__((ext_vector_type(8))) __bf16 bf16x8;
typedef __attribute__((ext_vector_type(4))) float f32x4;

#define GLOAD(g, l) __builtin_amdgcn_global_load_lds(                      \
    (const __attribute__((address_space(1))) void*)(g),                    \
    (__attribute__((address_space(3))) void*)(l), 16, 0, 0)

#define MFMA __builtin_amdgcn_mfma_f32_16x16x32_bf16

__device__ __forceinline__ unsigned short f2bf(float f) {
  unsigned u = __float_as_uint(f);
  u = (u + 0x7FFFu + ((u >> 16) & 1u)) >> 16;
  return (unsigned short)u;
}

// ---- W -> sign(W) as bf16 bits, plus per-block partial sums of |W| ------
__global__ __launch_bounds__(256) void wsign_kernel(
    const float* __restrict__ W, unsigned short* __restrict__ S,
    float* __restrict__ partials) {
  const int tid = threadIdx.x;
  const int stride = gridDim.x * 256;
  const int total4 = (4096 * 4096) / 4;
  float s = 0.f;
  for (int i = blockIdx.x * 256 + tid; i < total4; i += stride) {
    float4 w = reinterpret_cast<const float4*>(W)[i];
    ushort4 o;
    o.x = w.x > 0.f ? 0x3F80 : (w.x < 0.f ? 0xBF80 : 0);
    o.y = w.y > 0.f ? 0x3F80 : (w.y < 0.f ? 0xBF80 : 0);
    o.z = w.z > 0.f ? 0x3F80 : (w.z < 0.f ? 0xBF80 : 0);
    o.w = w.w > 0.f ? 0x3F80 : (w.w < 0.f ? 0xBF80 : 0);
    reinterpret_cast<ushort4*>(S)[i] = o;
    s += fabsf(w.x) + fabsf(w.y) + fabsf(w.z) + fabsf(w.w);
  }
#pragma unroll
  for (int off = 32; off > 0; off >>= 1) s += __shfl_down(s, off, 64);
  __shared__ float sm[4];
  if ((tid & 63) == 0) sm[tid >> 6] = s;
  __syncthreads();
  if (tid == 0) partials[blockIdx.x] = sm[0] + sm[1] + sm[2] + sm[3];
}

// ---- x f32 -> bf16 ------------------------------------------------------
__global__ __launch_bounds__(256) void xconv_kernel(
    const float* __restrict__ X, unsigned short* __restrict__ XB) {
  const int total4 = (8192 * 4096) / 4;
  const int stride = gridDim.x * 256;
  for (int i = blockIdx.x * 256 + threadIdx.x; i < total4; i += stride) {
    float4 v = reinterpret_cast<const float4*>(X)[i];
    ushort4 o;
    o.x = f2bf(v.x);
    o.y = f2bf(v.y);
    o.z = f2bf(v.z);
    o.w = f2bf(v.w);
    reinterpret_cast<ushort4*>(XB)[i] = o;
  }
}

// ---- deterministic reduce of partials -> scale = mean(|W|) --------------
__global__ __launch_bounds__(256) void finalize_kernel(
    const float* __restrict__ partials, float* __restrict__ scale) {
  const int tid = threadIdx.x;
  float s = 0.f;
  for (int i = tid; i < 2048; i += 256) s += partials[i];
#pragma unroll
  for (int off = 32; off > 0; off >>= 1) s += __shfl_down(s, off, 64);
  __shared__ float sm[4];
  if ((tid & 63) == 0) sm[tid >> 6] = s;
  __syncthreads();
  if (tid == 0) scale[0] = (sm[0] + sm[1] + sm[2] + sm[3]) * (1.0f / 16777216.0f);
}

// ---- 256x256x64 8-wave 4-phase bf16 GEMM, C = scale * A * B^T -----------
// 2-tiles-ahead pipeline: stage B(t+2) at P1, A(t+2) at P3; tile-top vmcnt(8).
// LDS slots (16 KiB each): A[par][half] = par*2+half; B[par][half] = 4+par*2+half
__global__ __launch_bounds__(512, 2) void gemm_sign_kernel(
    const unsigned short* __restrict__ A,  // [8192][4096] bf16 bits
    const unsigned short* __restrict__ B,  // [4096][4096] bf16 sign
    const float* __restrict__ scale_p, float* __restrict__ C) {
  constexpr int M = 8192, N = 4096, K = 4096;
  constexpr int NT = K / 64;  // 64 K-tiles
  __shared__ __align__(16) unsigned short lds[65536];  // 128 KiB

  const int tid = threadIdx.x;
  const int wid = tid >> 6;
  const int lane = tid & 63;
  const int wr = wid >> 2;           // 0..1 : A half (M-rows)
  const int wc = wid & 3;            // 0..3 : 64-col group (B-rows)
  const int bh = wc >> 1;            // B half slot
  const int bsub = (wc & 1) * 4096;  // element offset within B slot
  const int fr = lane & 15;
  const int fq = lane >> 4;
  const int s0 = (fq ^ (fr & 7)) * 8;  // swizzled k-slot; kk=1 is s0^32

  // XCD-aware swizzle; nwg = 32*16 = 512, divisible by 8
  const int bid = blockIdx.x;
  const int swz = (bid & 7) * 64 + (bid >> 3);
  const int tm = swz >> 4, tn = swz & 15;

  // --- staging source addresses (per-thread, pre-inverse-swizzled) ---
  const int srow = tid >> 3;              // 0..63
  const int sg = (tid & 7) ^ (srow & 7);  // inverse-swizzled col-group
  const unsigned short* aSrc0 = A + (size_t)(tm * 256 + srow) * K + sg * 8;
  const unsigned short* aSrc1 = aSrc0 + (size_t)128 * K;
  const unsigned short* bSrc0 = B + (size_t)(tn * 256 + srow) * K + sg * 8;
  const unsigned short* bSrc1 = bSrc0 + (size_t)128 * K;

#define STAGE(srcBase, slotIdx, koff)                              \
  do {                                                             \
    const unsigned short* _s = (srcBase) + (koff);                 \
    unsigned short* _d = &lds[(slotIdx) * 8192 + wid * 512];       \
    GLOAD(_s, _d);                                                 \
    GLOAD(_s + (size_t)64 * K, _d + 4096);                         \
  } while (0)

  f32x4 acc[8][4];
#pragma unroll
  for (int m = 0; m < 8; ++m)
#pragma unroll
    for (int n = 0; n < 4; ++n) acc[m][n] = (f32x4){0.f, 0.f, 0.f, 0.f};

  // Prologue: full tiles 0 and 1, issue order [B(0) A(0) B(1) A(1)]
  STAGE(bSrc0, 4, 0);
  STAGE(bSrc1, 5, 0);
  STAGE(aSrc0, 0, 0);
  STAGE(aSrc1, 1, 0);
  STAGE(bSrc0, 6, 64);
  STAGE(bSrc1, 7, 64);
  STAGE(aSrc0, 2, 64);
  STAGE(aSrc1, 3, 64);

#define READ_A(dst, aS, mb)                                              \
  do {                                                                   \
    dst[0][0] = *(const bf16x8*)((aS) + (mb)*1024 + s0);                 \
    dst[0][1] = *(const bf16x8*)((aS) + (mb)*1024 + (s0 ^ 32));          \
    dst[1][0] = *(const bf16x8*)((aS) + (mb)*1024 + 1024 + s0);          \
    dst[1][1] = *(const bf16x8*)((aS) + (mb)*1024 + 1024 + (s0 ^ 32));   \
  } while (0)

#define PH_MFMA(av, r0)                                                  \
  do {                                                                   \
    __builtin_amdgcn_s_setprio(1);                                       \
    _Pragma("unroll") for (int i = 0; i < 2; ++i)                        \
        _Pragma("unroll") for (int n = 0; n < 4; ++n) {                  \
      acc[(r0) + i][n] = MFMA(av[i][0], bq[n][0], acc[(r0) + i][n], 0, 0, 0); \
      acc[(r0) + i][n] = MFMA(av[i][1], bq[n][1], acc[(r0) + i][n], 0, 0, 0); \
    }                                                                    \
    __builtin_amdgcn_s_setprio(0);                                       \
  } while (0)

  for (int t = 0; t < NT; ++t) {
    const int par = t & 1;
    const int k2 = (t + 2) * 64;
    // --- top-of-tile: counted wait; t+1's 8 loads stay in flight ---
    if (t == NT - 1) {
      asm volatile("s_waitcnt vmcnt(0)" ::: "memory");
    } else {
      asm volatile("s_waitcnt vmcnt(8)" ::: "memory");
    }
    __builtin_amdgcn_s_barrier();

    const unsigned short* aS = &lds[(par * 2 + wr) * 8192 + fr * 64];
    const unsigned short* bS = &lds[(4 + par * 2 + bh) * 8192 + bsub + fr * 64];

    // ---- P0: read all B + A m0/m1 (no staging) ----
    bf16x8 bq[4][2];
#pragma unroll
    for (int n = 0; n < 4; ++n) {
      bq[n][0] = *(const bf16x8*)(bS + n * 1024 + s0);
      bq[n][1] = *(const bf16x8*)(bS + n * 1024 + (s0 ^ 32));
    }
    bf16x8 a01[2][2];
    READ_A(a01, aS, 0);
    __builtin_amdgcn_s_barrier();
    asm volatile("s_waitcnt lgkmcnt(0)" ::: "memory");
    PH_MFMA(a01, 0);
    __builtin_amdgcn_s_barrier();

    // ---- P1: read A m2/m3; stage B(t+2) (B[par] free since P0 barrier) ----
    bf16x8 a23[2][2];
    READ_A(a23, aS, 2);
    if (t + 2 < NT) {
      STAGE(bSrc0, 4 + par * 2, k2);
      STAGE(bSrc1, 4 + par * 2 + 1, k2);
    }
    __builtin_amdgcn_s_barrier();
    asm volatile("s_waitcnt lgkmcnt(0)" ::: "memory");
    PH_MFMA(a23, 2);
    __builtin_amdgcn_s_barrier();

    // ---- P2: read A m4..m7 ----
    bf16x8 a45[2][2], a67[2][2];
    READ_A(a45, aS, 4);
    READ_A(a67, aS, 6);
    __builtin_amdgcn_s_barrier();
    asm volatile("s_waitcnt lgkmcnt(0)" ::: "memory");
    PH_MFMA(a45, 4);
    __builtin_amdgcn_s_barrier();

    // ---- P3: stage A(t+2) (A[par] reads drained at P2's lgkm + barrier) ----
    if (t + 2 < NT) {
      STAGE(aSrc0, par * 2, k2);
      STAGE(aSrc1, par * 2 + 1, k2);
    }
    PH_MFMA(a67, 6);
    // no end barrier: top-of-tile vmcnt+barrier provides the needed sync
  }

  // ---- epilogue ----
  const float sc = *scale_p;
  const int crow0 = tm * 256 + wr * 128 + fq * 4;
  const int ccol0 = tn * 256 + wc * 64 + fr;
#pragma unroll
  for (int m = 0; m < 8; ++m) {
#pragma unroll
    for (int n = 0; n < 4; ++n) {
      f32x4 v = acc[m][n];
      float* cp = C + (size_t)(crow0 + m * 16) * N + ccol0 + n * 16;
#pragma unroll
      for (int j = 0; j < 4; ++j) cp[(size_t)j * N] = v[j] * sc;
    }
  }
#undef STAGE
#undef READ_A
#undef PH_MFMA
}

extern "C" void kernel_launch(void* const* d_in, const int* in_sizes, int n_in,
                              void* d_out, int out_size, void* d_ws,
                              size_t ws_size, hipStream_t stream) {
  const float* x = (const float*)d_in[0];   // [8192][4096] f32
  const float* w = (const float*)d_in[1];   // [4096][4096] f32
  float* out = (float*)d_out;               // [8192][4096] f32

  char* ws = (char*)d_ws;
  unsigned short* xb = (unsigned short*)ws;                   // 64 MiB
  unsigned short* sb = (unsigned short*)(ws + 67108864);      // 32 MiB
  float* partials = (float*)(ws + 100663296);                 // 2048 f32
  float* scale = (float*)(ws + 100663296 + 8192);             // 1 f32

  wsign_kernel<<<2048, 256, 0, stream>>>(w, sb, partials);
  xconv_kernel<<<2048, 256, 0, stream>>>(x, xb);
  finalize_kernel<<<1, 256, 0, stream>>>(partials, scale);
  gemm_sign_kernel<<<512, 512, 0, stream>>>(xb, sb, scale, out);
}

// Round 4
// 276.979 us; speedup vs baseline: 1.3069x; 1.0079x over previous
//
#include <hip/hip_runtime.h>
#include <hip/hip_bf16.h>
#include <stdint.h>

typedef __attribute__((ext_vector_type(8))) __bf16 bf16x8;
typedef __attribute__((ext_vector_type(4))) float f32x4;

#define GLOAD(g, l) __builtin_amdgcn_global_load_lds(                      \
    (const __attribute__((address_space(1))) void*)(g),                    \
    (__attribute__((address_space(3))) void*)(l), 16, 0, 0)

#define MFMA __builtin_amdgcn_mfma_f32_16x16x32_bf16
#define SB0 __builtin_amdgcn_sched_barrier(0)

__device__ __forceinline__ unsigned short f2bf(float f) {
  unsigned u = __float_as_uint(f);
  u = (u + 0x7FFFu + ((u >> 16) & 1u)) >> 16;
  return (unsigned short)u;
}

// ---- W -> sign(W) as bf16 bits, plus per-block partial sums of |W| ------
__global__ __launch_bounds__(256) void wsign_kernel(
    const float* __restrict__ W, unsigned short* __restrict__ S,
    float* __restrict__ partials) {
  const int tid = threadIdx.x;
  const int stride = gridDim.x * 256;
  const int total4 = (4096 * 4096) / 4;
  float s = 0.f;
  for (int i = blockIdx.x * 256 + tid; i < total4; i += stride) {
    float4 w = reinterpret_cast<const float4*>(W)[i];
    ushort4 o;
    o.x = w.x > 0.f ? 0x3F80 : (w.x < 0.f ? 0xBF80 : 0);
    o.y = w.y > 0.f ? 0x3F80 : (w.y < 0.f ? 0xBF80 : 0);
    o.z = w.z > 0.f ? 0x3F80 : (w.z < 0.f ? 0xBF80 : 0);
    o.w = w.w > 0.f ? 0x3F80 : (w.w < 0.f ? 0xBF80 : 0);
    reinterpret_cast<ushort4*>(S)[i] = o;
    s += fabsf(w.x) + fabsf(w.y) + fabsf(w.z) + fabsf(w.w);
  }
#pragma unroll
  for (int off = 32; off > 0; off >>= 1) s += __shfl_down(s, off, 64);
  __shared__ float sm[4];
  if ((tid & 63) == 0) sm[tid >> 6] = s;
  __syncthreads();
  if (tid == 0) partials[blockIdx.x] = sm[0] + sm[1] + sm[2] + sm[3];
}

// ---- x f32 -> bf16 ------------------------------------------------------
__global__ __launch_bounds__(256) void xconv_kernel(
    const float* __restrict__ X, unsigned short* __restrict__ XB) {
  const int total4 = (8192 * 4096) / 4;
  const int stride = gridDim.x * 256;
  for (int i = blockIdx.x * 256 + threadIdx.x; i < total4; i += stride) {
    float4 v = reinterpret_cast<const float4*>(X)[i];
    ushort4 o;
    o.x = f2bf(v.x);
    o.y = f2bf(v.y);
    o.z = f2bf(v.z);
    o.w = f2bf(v.w);
    reinterpret_cast<ushort4*>(XB)[i] = o;
  }
}

// ---- deterministic reduce of partials -> scale = mean(|W|) --------------
__global__ __launch_bounds__(256) void finalize_kernel(
    const float* __restrict__ partials, float* __restrict__ scale) {
  const int tid = threadIdx.x;
  float s = 0.f;
  for (int i = tid; i < 2048; i += 256) s += partials[i];
#pragma unroll
  for (int off = 32; off > 0; off >>= 1) s += __shfl_down(s, off, 64);
  __shared__ float sm[4];
  if ((tid & 63) == 0) sm[tid >> 6] = s;
  __syncthreads();
  if (tid == 0) scale[0] = (sm[0] + sm[1] + sm[2] + sm[3]) * (1.0f / 16777216.0f);
}

// ---- 256x256x64 8-wave bf16 GEMM, C = scale * A * B^T -------------------
// Counted-lgkm register pipeline: all 24 ds_reads issued up front (ordered
// groups), quadrant MFMAs gated by lgkmcnt(4/8/4/0) so LDS reads overlap
// MFMA. 2 barriers/tile. Stages: A1(t+1), B0/B1/A0(t+2) after mid-barrier;
// tile-top vmcnt(6) drains exactly tile t's 4 halves (FIFO-audited).
// LDS slots (16 KiB): A[par][half] = par*2+half; B[par][half] = 4+par*2+half
__global__ __launch_bounds__(512, 2) void gemm_sign_kernel(
    const unsigned short* __restrict__ A,  // [8192][4096] bf16 bits
    const unsigned short* __restrict__ B,  // [4096][4096] bf16 sign
    const float* __restrict__ scale_p, float* __restrict__ C) {
  constexpr int M = 8192, N = 4096, K = 4096;
  constexpr int NT = K / 64;  // 64 K-tiles
  __shared__ __align__(16) unsigned short lds[65536];  // 128 KiB

  const int tid = threadIdx.x;
  const int wid = tid >> 6;
  const int lane = tid & 63;
  const int wr = wid >> 2;           // 0..1 : A half (M-rows)
  const int wc = wid & 3;            // 0..3 : 64-col group (B-rows)
  const int bh = wc >> 1;            // B half slot
  const int bsub = (wc & 1) * 4096;  // element offset within B slot
  const int fr = lane & 15;
  const int fq = lane >> 4;
  const int s0 = (fq ^ (fr & 7)) * 8;  // swizzled k-slot; kk=1 is s0^32

  // XCD-aware swizzle; nwg = 32*16 = 512, divisible by 8
  const int bid = blockIdx.x;
  const int swz = (bid & 7) * 64 + (bid >> 3);
  const int tm = swz >> 4, tn = swz & 15;

  // --- staging source addresses (per-thread, pre-inverse-swizzled) ---
  const int srow = tid >> 3;              // 0..63
  const int sg = (tid & 7) ^ (srow & 7);  // inverse-swizzled col-group
  const unsigned short* aSrc0 = A + (size_t)(tm * 256 + srow) * K + sg * 8;
  const unsigned short* aSrc1 = aSrc0 + (size_t)128 * K;
  const unsigned short* bSrc0 = B + (size_t)(tn * 256 + srow) * K + sg * 8;
  const unsigned short* bSrc1 = bSrc0 + (size_t)128 * K;

#define STAGE(srcBase, slotIdx, koff)                              \
  do {                                                             \
    const unsigned short* _s = (srcBase) + (koff);                 \
    unsigned short* _d = &lds[(slotIdx) * 8192 + wid * 512];       \
    GLOAD(_s, _d);                                                 \
    GLOAD(_s + (size_t)64 * K, _d + 4096);                         \
  } while (0)

  f32x4 acc[8][4];
#pragma unroll
  for (int m = 0; m < 8; ++m)
#pragma unroll
    for (int n = 0; n < 4; ++n) acc[m][n] = (f32x4){0.f, 0.f, 0.f, 0.f};

  // Prologue: tile0 all 4 halves, then B0(1),B1(1),A0(1). A1(1) staged in t=0.
  STAGE(bSrc0, 4, 0);
  STAGE(bSrc1, 5, 0);
  STAGE(aSrc0, 0, 0);
  STAGE(aSrc1, 1, 0);
  STAGE(bSrc0, 6, 64);
  STAGE(bSrc1, 7, 64);
  STAGE(aSrc0, 2, 64);

#define READ_A(dst, aS, mb)                                              \
  do {                                                                   \
    dst[0][0] = *(const bf16x8*)((aS) + (mb)*1024 + s0);                 \
    dst[0][1] = *(const bf16x8*)((aS) + (mb)*1024 + (s0 ^ 32));          \
    dst[1][0] = *(const bf16x8*)((aS) + (mb)*1024 + 1024 + s0);          \
    dst[1][1] = *(const bf16x8*)((aS) + (mb)*1024 + 1024 + (s0 ^ 32));   \
  } while (0)

#define PH_MFMA(av, r0)                                                  \
  do {                                                                   \
    __builtin_amdgcn_s_setprio(1);                                       \
    _Pragma("unroll") for (int i = 0; i < 2; ++i)                        \
        _Pragma("unroll") for (int n = 0; n < 4; ++n) {                  \
      acc[(r0) + i][n] = MFMA(av[i][0], bq[n][0], acc[(r0) + i][n], 0, 0, 0); \
      acc[(r0) + i][n] = MFMA(av[i][1], bq[n][1], acc[(r0) + i][n], 0, 0, 0); \
    }                                                                    \
    __builtin_amdgcn_s_setprio(0);                                       \
  } while (0)

  for (int t = 0; t < NT; ++t) {
    const int par = t & 1;
    const int opp = par ^ 1;
    // --- tile top: counted wait drains exactly tile t's 4 halves ---
    if (t == NT - 1) {
      asm volatile("s_waitcnt vmcnt(0)" ::: "memory");
    } else {
      asm volatile("s_waitcnt vmcnt(6)" ::: "memory");
    }
    __builtin_amdgcn_s_barrier();

    const unsigned short* aS = &lds[(par * 2 + wr) * 8192 + fr * 64];
    const unsigned short* bS = &lds[(4 + par * 2 + bh) * 8192 + bsub + fr * 64];

    // ---- issue group 1a: bq (8 reads) + a01 (4 reads) ----
    bf16x8 bq[4][2];
#pragma unroll
    for (int n = 0; n < 4; ++n) {
      bq[n][0] = *(const bf16x8*)(bS + n * 1024 + s0);
      bq[n][1] = *(const bf16x8*)(bS + n * 1024 + (s0 ^ 32));
    }
    bf16x8 a01[2][2];
    READ_A(a01, aS, 0);
    SB0;  // keep group 1a oldest
    // ---- issue group 1b: a23 (4 reads) ----
    bf16x8 a23[2][2];
    READ_A(a23, aS, 2);
    // wait: bq+a01 done, a23 (4) in flight
    asm volatile("s_waitcnt lgkmcnt(4)" ::: "memory");
    SB0;
    PH_MFMA(a01, 0);  // q0 overlaps a23 completion

    // ---- issue group 2a: a45; group 2b: a67 ----
    bf16x8 a45[2][2], a67[2][2];
    READ_A(a45, aS, 4);
    SB0;
    READ_A(a67, aS, 6);
    // wait: a23 done, a45+a67 (8) in flight
    asm volatile("s_waitcnt lgkmcnt(8)" ::: "memory");
    SB0;
    PH_MFMA(a23, 2);  // q1 overlaps a45/a67 completion

    asm volatile("s_waitcnt lgkmcnt(4)" ::: "memory");
    SB0;
    PH_MFMA(a45, 4);  // q2 overlaps a67 completion

    asm volatile("s_waitcnt lgkmcnt(0)" ::: "memory");
    SB0;
    __builtin_amdgcn_s_barrier();  // block-wide: all tile-t LDS reads done

    // ---- stages (issue order defines vmcnt FIFO) ----
    if (t + 1 < NT) STAGE(aSrc1, opp * 2 + 1, (t + 1) * 64);   // A1(t+1)
    if (t + 2 < NT) {
      const int k2 = (t + 2) * 64;
      STAGE(bSrc0, 4 + par * 2, k2);      // B0(t+2)
      STAGE(bSrc1, 4 + par * 2 + 1, k2);  // B1(t+2)
      STAGE(aSrc0, par * 2, k2);          // A0(t+2)
    }
    PH_MFMA(a67, 6);  // q3 overlaps stage issue + HBM latency
  }

  // ---- epilogue ----
  const float sc = *scale_p;
  const int crow0 = tm * 256 + wr * 128 + fq * 4;
  const int ccol0 = tn * 256 + wc * 64 + fr;
#pragma unroll
  for (int m = 0; m < 8; ++m) {
#pragma unroll
    for (int n = 0; n < 4; ++n) {
      f32x4 v = acc[m][n];
      float* cp = C + (size_t)(crow0 + m * 16) * N + ccol0 + n * 16;
#pragma unroll
      for (int j = 0; j < 4; ++j) cp[(size_t)j * N] = v[j] * sc;
    }
  }
#undef STAGE
#undef READ_A
#undef PH_MFMA
}

extern "C" void kernel_launch(void* const* d_in, const int* in_sizes, int n_in,
                              void* d_out, int out_size, void* d_ws,
                              size_t ws_size, hipStream_t stream) {
  const float* x = (const float*)d_in[0];   // [8192][4096] f32
  const float* w = (const float*)d_in[1];   // [4096][4096] f32
  float* out = (float*)d_out;               // [8192][4096] f32

  char* ws = (char*)d_ws;
  unsigned short* xb = (unsigned short*)ws;                   // 64 MiB
  unsigned short* sb = (unsigned short*)(ws + 67108864);      // 32 MiB
  float* partials = (float*)(ws + 100663296);                 // 2048 f32
  float* scale = (float*)(ws + 100663296 + 8192);             // 1 f32

  wsign_kernel<<<2048, 256, 0, stream>>>(w, sb, partials);
  xconv_kernel<<<2048, 256, 0, stream>>>(x, xb);
  finalize_kernel<<<1, 256, 0, stream>>>(partials, scale);
  gemm_sign_kernel<<<512, 512, 0, stream>>>(xb, sb, scale, out);
}